// Round 9
// baseline (655.290 us; speedup 1.0000x reference)
//
#include <hip/hip_runtime.h>

#define N_NODES 50000
#define N_EDGES 600000
#define F_NODE 128
#define F_EDGE 32
#define MSG 32
#define NPB 32          // nodes per fused block -> 1563 blocks (6.1/CU)
#define CHK 128         // edges per chunk
#define QB64 ((N_NODES + 63) / 64)                 // 782 (prep GEMM tiles)
#define FBLOCKS ((N_NODES + NPB - 1) / NPB)        // 1563
#define CBLOCKS ((N_EDGES + 255) / 256)            // 2344

typedef float v2f __attribute__((ext_vector_type(2)));   // -> v_pk_fma_f32

// bf16 helpers
__device__ __forceinline__ unsigned short f2bf(float f) {
    union { float f; unsigned int u; } v; v.f = f;
    unsigned int r = v.u + 0x7fffu + ((v.u >> 16) & 1u);
    return (unsigned short)(r >> 16);
}

// Raw barrier: lgkmcnt(0)-only fence + s_barrier (no vmcnt drain ->
// prefetched global loads stay in flight across barriers).
#define BAR_LGKM() do {                                           \
    asm volatile("s_waitcnt lgkmcnt(0)" ::: "memory");            \
    __builtin_amdgcn_s_barrier();                                 \
    asm volatile("" ::: "memory");                                \
} while (0)

// ---------------------------------------------------------------------------
// hist_kernel, 3 block ranges:
//  [0, QB64): dual node-term GEMM  P0 = nf@We[0:128]+be, Q = nf@We[128:256]
//  [QB64, 2*QB64): OP = nf@Wn[0:128] + bn -> bf16  (v9: phase-2 nf-part
//     hoisted out of fused; weights staged in LDS — v8's global-weight read
//     was falsified, LDS restored)
//  [2*QB64, ..): degree histogram WITH RANK CAPTURE (rank[e] = old count)
// ---------------------------------------------------------------------------
__global__ __launch_bounds__(256)
void hist_kernel(const float* __restrict__ nf,
                 const float* __restrict__ We,     // [288][32]
                 const float* __restrict__ be,     // [32]
                 const float* __restrict__ Wn,     // [160][128]
                 const float* __restrict__ bn,     // [128]
                 const int* __restrict__ idx,      // [2][E]
                 unsigned short* __restrict__ Q,   // [N][32] bf16
                 unsigned short* __restrict__ P0g, // [N][32] bf16
                 unsigned short* __restrict__ OP,  // [N][128] bf16
                 int* __restrict__ deg,            // [N] counts
                 int* __restrict__ rank)           // [E]
{
    __shared__ __align__(16) float S[6144];
    const int tid = threadIdx.x;

    if (blockIdx.x >= 2 * QB64) {
        int e = (blockIdx.x - 2 * QB64) * 256 + tid;
        if (e < N_EDGES) {
            int n = idx[e];
            if ((unsigned)n >= (unsigned)N_NODES) n = 0;
            rank[e] = atomicAdd(&deg[n], 1);
        }
        return;
    }

    if (blockIdx.x >= QB64) {
        // ---- branch B: OP = nf @ Wn[0:128] + bn -> bf16 ----
        float* sInT = S;            // [32][64]
        float* sWn  = S + 2048;     // [32][128]
        const int n0b = (blockIdx.x - QB64) * 64;
        const int png2 = tid >> 4;  // nodes 4*png2..+3
        const int pcg2 = tid & 15;  // cols 4*pcg2..+3 and 64+4*pcg2..+3

        v2f accC[8][2];             // [col j][node pair p]
#pragma unroll
        for (int j = 0; j < 8; ++j) { accC[j][0] = (v2f){0.f,0.f}; accC[j][1] = (v2f){0.f,0.f}; }

        for (int kc = 0; kc < 4; ++kc) {
            __syncthreads();
            {
                const float4* w4 = (const float4*)(Wn + (size_t)kc * 32 * 128);
                float4* s4 = (float4*)sWn;
#pragma unroll
                for (int i = 0; i < 4; ++i) s4[tid + 256 * i] = w4[tid + 256 * i];
            }
            {
                int nl = tid >> 2, q = tid & 3;
                int n = n0b + nl; if (n >= N_NODES) n = N_NODES - 1;
                const float4* src4 = (const float4*)(nf + (size_t)n * F_NODE + kc * 32);
#pragma unroll
                for (int h = 0; h < 2; ++h) {
                    float4 v = src4[q * 2 + h];
                    int kl = q * 8 + h * 4;
                    sInT[(kl + 0) * 64 + nl] = v.x;
                    sInT[(kl + 1) * 64 + nl] = v.y;
                    sInT[(kl + 2) * 64 + nl] = v.z;
                    sInT[(kl + 3) * 64 + nl] = v.w;
                }
            }
            __syncthreads();
#pragma unroll
            for (int k = 0; k < 32; ++k) {
                float4 m4 = *(const float4*)&sInT[k * 64 + 4 * png2];
                float4 w0 = *(const float4*)&sWn[k * 128 + 4 * pcg2];
                float4 w1 = *(const float4*)&sWn[k * 128 + 64 + 4 * pcg2];
                v2f m01 = (v2f){m4.x, m4.y}, m23 = (v2f){m4.z, m4.w};
                accC[0][0] += m01 * w0.x; accC[0][1] += m23 * w0.x;
                accC[1][0] += m01 * w0.y; accC[1][1] += m23 * w0.y;
                accC[2][0] += m01 * w0.z; accC[2][1] += m23 * w0.z;
                accC[3][0] += m01 * w0.w; accC[3][1] += m23 * w0.w;
                accC[4][0] += m01 * w1.x; accC[4][1] += m23 * w1.x;
                accC[5][0] += m01 * w1.y; accC[5][1] += m23 * w1.y;
                accC[6][0] += m01 * w1.z; accC[6][1] += m23 * w1.z;
                accC[7][0] += m01 * w1.w; accC[7][1] += m23 * w1.w;
            }
        }
        float4 b0 = *(const float4*)(bn + 4 * pcg2);
        float4 b1 = *(const float4*)(bn + 64 + 4 * pcg2);
#pragma unroll
        for (int p = 0; p < 2; ++p)
#pragma unroll
            for (int l = 0; l < 2; ++l) {
                int n = n0b + 4 * png2 + 2 * p + l;
                if (n < N_NODES) {
                    ushort4 o0, o1;
                    o0.x = f2bf(accC[0][p][l] + b0.x);
                    o0.y = f2bf(accC[1][p][l] + b0.y);
                    o0.z = f2bf(accC[2][p][l] + b0.z);
                    o0.w = f2bf(accC[3][p][l] + b0.w);
                    o1.x = f2bf(accC[4][p][l] + b1.x);
                    o1.y = f2bf(accC[5][p][l] + b1.y);
                    o1.z = f2bf(accC[6][p][l] + b1.z);
                    o1.w = f2bf(accC[7][p][l] + b1.w);
                    *(ushort4*)(OP + (size_t)n * F_NODE + 4 * pcg2) = o0;
                    *(ushort4*)(OP + (size_t)n * F_NODE + 64 + 4 * pcg2) = o1;
                }
            }
        return;
    }

    // ---- branch A: dual P0/Q GEMM (proven) ----
    {
        float* sInT = S;            // [32][64]
        float* sWeA = S + 2048;     // [32][32]
        float* sWeB = S + 3072;     // [32][32]
        const int n0b = blockIdx.x * 64;
        const int ng = tid & 31;
        const int og = tid >> 5;

        v2f accA[4], accB[4];
#pragma unroll
        for (int j = 0; j < 4; ++j) { accA[j] = (v2f){0.f, 0.f}; accB[j] = (v2f){0.f, 0.f}; }

        for (int kc = 0; kc < 4; ++kc) {
            __syncthreads();
            ((float4*)sWeA)[tid] = ((const float4*)(We + kc * 32 * MSG))[tid];
            ((float4*)sWeB)[tid] = ((const float4*)(We + (128 + kc * 32) * MSG))[tid];
            {
                int nl = tid >> 2, q = tid & 3;
                int n = n0b + nl; if (n >= N_NODES) n = N_NODES - 1;
                const float4* src4 = (const float4*)(nf + (size_t)n * F_NODE + kc * 32);
#pragma unroll
                for (int h = 0; h < 2; ++h) {
                    float4 v = src4[q * 2 + h];
                    int kl = q * 8 + h * 4;
                    sInT[(kl + 0) * 64 + nl] = v.x;
                    sInT[(kl + 1) * 64 + nl] = v.y;
                    sInT[(kl + 2) * 64 + nl] = v.z;
                    sInT[(kl + 3) * 64 + nl] = v.w;
                }
            }
            __syncthreads();
#pragma unroll
            for (int k = 0; k < 32; ++k) {
                v2f m = *(const v2f*)&sInT[k * 64 + 2 * ng];
                float4 wa = *(const float4*)&sWeA[k * 32 + og * 4];
                float4 wb = *(const float4*)&sWeB[k * 32 + og * 4];
                accA[0] += m * wa.x; accA[1] += m * wa.y;
                accA[2] += m * wa.z; accA[3] += m * wa.w;
                accB[0] += m * wb.x; accB[1] += m * wb.y;
                accB[2] += m * wb.z; accB[3] += m * wb.w;
            }
        }
        float bloc[4];
#pragma unroll
        for (int j = 0; j < 4; ++j) bloc[j] = be[og * 4 + j];
#pragma unroll
        for (int i = 0; i < 2; ++i) {
            int n = n0b + 2 * ng + i;
            if (n < N_NODES) {
                ushort4 oq, op;
                oq.x = f2bf(accB[0][i]); oq.y = f2bf(accB[1][i]);
                oq.z = f2bf(accB[2][i]); oq.w = f2bf(accB[3][i]);
                op.x = f2bf(accA[0][i] + bloc[0]); op.y = f2bf(accA[1][i] + bloc[1]);
                op.z = f2bf(accA[2][i] + bloc[2]); op.w = f2bf(accA[3][i] + bloc[3]);
                *(ushort4*)(Q   + (size_t)n * MSG + og * 4) = oq;
                *(ushort4*)(P0g + (size_t)n * MSG + og * 4) = op;
            }
        }
    }
}

// ---------------------------------------------------------------------------
// scan v3 (proven): int4 per thread, in-place exclusive scan counts->starts.
// ---------------------------------------------------------------------------
__global__ __launch_bounds__(1024)
void scan_kernel(int* __restrict__ deg_cursor) {
    __shared__ int wsum[16];
    __shared__ int wpre[16];
    const int t = threadIdx.x;
    const int lane = t & 63;
    const int wid = t >> 6;
    const int N4 = N_NODES / 4;              // 12500
    const int NT = (N4 + 1023) / 1024;       // 13
    int run = 0;
    int4 vnext = make_int4(0, 0, 0, 0);
    if (t < N4) vnext = ((const int4*)deg_cursor)[t];
    for (int tt = 0; tt < NT; ++tt) {
        int4 v = vnext;
        if (tt + 1 < NT) {
            int ni = (tt + 1) * 1024 + t;
            vnext = (ni < N4) ? ((const int4*)deg_cursor)[ni] : make_int4(0, 0, 0, 0);
        }
        int s = v.x + v.y + v.z + v.w;
        int x = s;
#pragma unroll
        for (int d = 1; d < 64; d <<= 1) {
            int u = __shfl_up(x, (unsigned)d, 64);
            if (lane >= d) x += u;
        }
        if (lane == 63) wsum[wid] = x;
        BAR_LGKM();
        if (wid == 0) {
            int ss = (lane < 16) ? wsum[lane] : 0;
#pragma unroll
            for (int d = 1; d < 16; d <<= 1) {
                int u = __shfl_up(ss, (unsigned)d, 64);
                if (lane >= d) ss += u;
            }
            if (lane < 16) wpre[lane] = ss;
        }
        BAR_LGKM();
        int wexcl = (wid > 0) ? wpre[wid - 1] : 0;
        int total = wpre[15];
        int i4 = tt * 1024 + t;
        if (i4 < N4) {
            int base = run + wexcl + (x - s);
            int4 o;
            o.x = base;
            o.y = base + v.x;
            o.z = base + v.x + v.y;
            o.w = base + v.x + v.y + v.z;
            ((int4*)deg_cursor)[i4] = o;
        }
        run += total;
        BAR_LGKM();
    }
}

// ---------------------------------------------------------------------------
// place: perm[start[n] + rank[e]] = e — NO atomics. (proven)
// ---------------------------------------------------------------------------
__global__ void place_kernel(const int* __restrict__ idx,
                             const int* __restrict__ startArr,
                             const int* __restrict__ rank,
                             int* __restrict__ perm) {
    int e = blockIdx.x * 256 + threadIdx.x;
    if (e < N_EDGES) {
        int n = idx[e];
        if ((unsigned)n >= (unsigned)N_NODES) n = 0;
        int p = startArr[n] + rank[e];
        if ((unsigned)p < (unsigned)N_EDGES) perm[p] = e;
    }
}

// ---------------------------------------------------------------------------
// Fused kernel v9 — v7 chunk loop (proven 92 µs; v8's global-weight read
// falsified and reverted) + phase-2 collapsed to one kc slab:
//   out = relu(OP + msum @ Wn[128:160])
// Phase-2 LDS ops/thread: ~340 -> ~72 (stage 8 + 64 GEMM reads).
// Numerics: A+B f32 reorder + bf16 OP (~0.006 abs) — well under threshold.
// LDS 38.7 KB -> 4 blocks/CU. __launch_bounds__(256,4).
// LDS map (floats): [0,4096) sBuf | [4096,8192) sMsg | [8192,9216) sWeC
//   | [9216,9728) sP0h(u16) | [9728,9856) sNL | [9856..] sOff
// Phase2 overlay: sWn2 = S[0,4096), sInT2 = S+4096.
// ---------------------------------------------------------------------------
__global__ __launch_bounds__(256, 4)
void fused_kernel(const float* __restrict__ nf,
                  const int* __restrict__ idx,      // [2][E]
                  const float* __restrict__ ef,     // [E][32]
                  const float* __restrict__ We,     // [288][32]
                  const float* __restrict__ Wn,     // [160][128]
                  const int* __restrict__ perm,     // [E] sorted edge ids
                  const int* __restrict__ startArr, // [N] start offsets
                  const unsigned short* __restrict__ Q,    // [N][32] bf16
                  const unsigned short* __restrict__ P0g,  // [N][32] bf16
                  const unsigned short* __restrict__ OP,   // [N][128] bf16
                  float* __restrict__ out)          // [N][128]
{
    __shared__ __align__(16) float S[9892];
    float* sBuf = S;                                  // [32][128] ef^T
    float* sMsg = S + 4096;                           // [32][128] msgT
    float* sWeC = S + 8192;                           // [32][32] We_bot
    unsigned short* sP0h = (unsigned short*)(S + 9216); // [32][32] bf16
    int* sNL  = (int*)(S + 9728);                     // [128] (ln<<20)|n1
    int* sOff = (int*)(S + 9856);                     // [33]
    float* sWn2  = S;                                 // phase2 Wn bottom slab
    float* sInT2 = S + 4096;                          // phase2 msum^T (overlay)

    const int tid = threadIdx.x;
    const int n0b = blockIdx.x * NPB;

    if (tid <= NPB) {
        int nn = n0b + tid;
        int v = (nn < N_NODES) ? startArr[nn] : N_EDGES;
        if (v < 0) v = 0;
        if (v > N_EDGES) v = N_EDGES;
        sOff[tid] = v;
    }
    ((float4*)sWeC)[tid] = ((const float4*)(We + 256 * MSG))[tid];  // We_bot
    if (tid < 128) {   // P0 rows for this block's 32 nodes (2 KB coalesced)
        int r = tid >> 2, c = (tid & 3) * 8;
        int n = n0b + r; if (n >= N_NODES) n = N_NODES - 1;
        *(uint4*)(sP0h + r * MSG + c) = *(const uint4*)(P0g + (size_t)n * MSG + c);
    }
    __syncthreads();

    const int rs = sOff[0];
    const int re = sOff[NPB];

    // persistent per-thread message sums: thread = (node rnl, cols rq4..+3)
    float msum[4];
#pragma unroll
    for (int j = 0; j < 4; ++j) msum[j] = 0.f;
    const int rnl = tid >> 3;            // node 0..31
    const int rq4 = (tid & 7) * 4;       // col group
    const int gx  = (rq4 >> 3) << 2;     // reduce-phase swizzle (matches store)

    const int eq = tid & 31;   // GEMM: edges 4eq..4eq+3
    const int cq = tid >> 5;   // GEMM: cols 4cq..4cq+3
    const int g1 = (cq >> 1) & 3;        // store row-group swizzle (const/thread)
    const int el = tid >> 1;   // staged edge slot 0..127
    const int h2 = tid & 1;    // which half of the ef row

    // ---- prefetch pipeline registers -------------------------------------
    int n1r = 0;                     // n1 for chunk i (h2==0 lanes)
    int pe_next = 0, pe_next2 = 0;   // perm for chunk i+1 / in flight i+2
    float4 efr[4];                   // my ef half-row for chunk i
#pragma unroll
    for (int q = 0; q < 4; ++q) efr[q] = make_float4(0.f, 0.f, 0.f, 0.f);

    if (rs < re) {
        int e0 = rs + el;
        int pe0 = 0;
        if (e0 < re) {
            pe0 = perm[e0];
            if ((unsigned)pe0 >= (unsigned)N_EDGES) pe0 = 0;   // poison guard
            if (h2 == 0) {
                int tn = idx[N_EDGES + pe0];
                if ((unsigned)tn >= (unsigned)N_NODES) tn = 0;
                n1r = tn;
            }
        }
        const float4* ef4 = (const float4*)(ef + (size_t)pe0 * F_EDGE + h2 * 16);
#pragma unroll
        for (int q = 0; q < 4; ++q) efr[q] = ef4[q];
        int e1 = rs + CHK + el;
        if (e1 < re) {
            int p = perm[e1];
            if ((unsigned)p >= (unsigned)N_EDGES) p = 0;
            pe_next = p;
        }
        pe_next2 = pe_next;          // bootstrap rotation for iter 0
    }

    // ================= Chunk loop (2 barriers) ============================
    for (int cs = rs; cs < re; cs += CHK) {
        pe_next = pe_next2;
        {
            // ---- stage ef^T(i) into sBuf (k-major, swizzled) ----
#pragma unroll
            for (int q = 0; q < 4; ++q) {
                float4 v = efr[q];
                int g = (h2 * 2 + (q >> 1)) & 3;              // (row>>3)&3 of this quad
                int ctw = ((el & ~3) ^ (g << 2)) + (el & 3);
                int r0 = (h2 * 16 + q * 4) * CHK;
                sBuf[r0 + 0 * CHK + ctw] = v.x;
                sBuf[r0 + 1 * CHK + ctw] = v.y;
                sBuf[r0 + 2 * CHK + ctw] = v.z;
                sBuf[r0 + 3 * CHK + ctw] = v.w;
            }
            // ---- ln (binary search over sOff[0..32]) + packed sNL ----
            if (h2 == 0) {
                int e = cs + el;
                int ln = 0;
                if (e < re) {
                    int lo = 0, hi = NPB;
#pragma unroll
                    for (int s = 0; s < 5; ++s) {
                        int mid = (lo + hi) >> 1;
                        if (sOff[mid] <= e) lo = mid; else hi = mid;
                    }
                    ln = lo;
                }
                sNL[el] = (ln << 20) | n1r;
            }
            // ---- issue gathers for chunk i+1 ----
            int e1 = cs + CHK + el;
            if (e1 < re) {
                int pe1 = pe_next;
                if (h2 == 0) {
                    int tn = idx[N_EDGES + pe1];
                    if ((unsigned)tn >= (unsigned)N_NODES) tn = 0;
                    n1r = tn;
                }
                const float4* ef4 = (const float4*)(ef + (size_t)pe1 * F_EDGE + h2 * 16);
#pragma unroll
                for (int q = 0; q < 4; ++q) efr[q] = ef4[q];
            } else if (h2 == 0) n1r = 0;
            // ---- issue perm for chunk i+2 ----
            int e2 = cs + 2 * CHK + el;
            if (e2 < re) {
                int p = perm[e2];
                if ((unsigned)p >= (unsigned)N_EDGES) p = 0;
                pe_next2 = p;
            } else pe_next2 = 0;
        }
        BAR_LGKM();        // (A) staging visible; prev reduce done (>=1 bar ago)

        // Q gather (4 edges x 4 cols = uint2 each), in flight during GEMM
        int4 nlq = *(const int4*)&sNL[4 * eq];
        int nlv[4] = { nlq.x, nlq.y, nlq.z, nlq.w };
        uint2 qv[4];
#pragma unroll
        for (int i = 0; i < 4; ++i)
            qv[i] = *(const uint2*)(Q + (size_t)(nlv[i] & 0xFFFFF) * MSG + cq * 4);

        v2f accp[4][2];                    // [col j][edge pair p]
#pragma unroll
        for (int j = 0; j < 4; ++j) { accp[j][0] = (v2f){0.f,0.f}; accp[j][1] = (v2f){0.f,0.f}; }

#pragma unroll
        for (int k = 0; k < 32; ++k) {
            float4 m4 = *(const float4*)&sBuf[k * CHK + ((4 * eq) ^ (((k >> 3) & 3) << 2))];
            float4 w  = *(const float4*)&sWeC[k * 32 + cq * 4];
            v2f m01 = (v2f){m4.x, m4.y}, m23 = (v2f){m4.z, m4.w};
            accp[0][0] += m01 * w.x; accp[0][1] += m23 * w.x;
            accp[1][0] += m01 * w.y; accp[1][1] += m23 * w.y;
            accp[2][0] += m01 * w.z; accp[2][1] += m23 * w.z;
            accp[3][0] += m01 * w.w; accp[3][1] += m23 * w.w;
        }

        // ---- +P0 +Q, relu, store msgT[col][edge] (b128 along edges) ----
        {
            uint2 pv[4];
#pragma unroll
            for (int i = 0; i < 4; ++i)
                pv[i] = *(const uint2*)(sP0h + (nlv[i] >> 20) * MSG + cq * 4);
            int sb = (4 * eq) ^ (g1 << 2);
#pragma unroll
            for (int j = 0; j < 4; ++j) {
                float sv[4];
#pragma unroll
                for (int i = 0; i < 4; ++i) {
                    unsigned qu = (j < 2) ? qv[i].x : qv[i].y;
                    unsigned pu = (j < 2) ? pv[i].x : pv[i].y;
                    float qf = __uint_as_float((j & 1) ? (qu & 0xffff0000u) : (qu << 16));
                    float pf = __uint_as_float((j & 1) ? (pu & 0xffff0000u) : (pu << 16));
                    sv[i] = fmaxf(accp[j][i >> 1][i & 1] + pf + qf, 0.f);
                }
                *(float4*)&sMsg[(cq * 4 + j) * CHK + sb] =
                    make_float4(sv[0], sv[1], sv[2], sv[3]);
            }
        }
        BAR_LGKM();        // (B) msgT visible; sBuf reads done (next stage safe)

        // ---- segmented reduction (no atomics): my node's range this chunk
        {
            int lo = sOff[rnl] - cs;     if (lo < 0) lo = 0;
            int hi = sOff[rnl + 1] - cs; if (hi > CHK) hi = CHK;
            for (int elr = lo; elr < hi; ++elr) {
                int ebase = ((elr & ~3) ^ gx) + (elr & 3);
#pragma unroll
                for (int j = 0; j < 4; ++j)
                    msum[j] += sMsg[(rq4 + j) * CHK + ebase];
            }
        }
    }

    // ====== Phase 2 (one slab): out = relu(OP + msum @ Wn[128:160]) ======
    const int png = tid & 7;       // nodes 4*png..+3
    const int pcg = tid >> 3;      // cols 4*pcg..+3

    __syncthreads();               // chunk-loop LDS reads done; overlay safe
    {
        const float4* w4 = (const float4*)(Wn + (size_t)128 * 128);
        float4* s4 = (float4*)sWn2;
#pragma unroll
        for (int i = 0; i < 4; ++i) s4[tid + 256 * i] = w4[tid + 256 * i];
        // thread (rnl, rq4) owns exactly msum for node rnl, cols rq4..+3
#pragma unroll
        for (int h = 0; h < 4; ++h) {
            int r = rq4 + h;
            sInT2[r * 32 + (rnl ^ ((r & 7) << 2))] = msum[h];
        }
    }
    __syncthreads();

    v2f acc2[4][2];                // [col j][node pair p]
#pragma unroll
    for (int j = 0; j < 4; ++j) { acc2[j][0] = (v2f){0.f,0.f}; acc2[j][1] = (v2f){0.f,0.f}; }

#pragma unroll
    for (int k = 0; k < 32; ++k) {
        float4 m4 = *(const float4*)&sInT2[k * 32 + ((4 * png) ^ ((k & 7) << 2))];
        float4 w  = *(const float4*)&sWn2[k * 128 + 4 * pcg];
        v2f m01 = (v2f){m4.x, m4.y}, m23 = (v2f){m4.z, m4.w};
        acc2[0][0] += m01 * w.x; acc2[0][1] += m23 * w.x;
        acc2[1][0] += m01 * w.y; acc2[1][1] += m23 * w.y;
        acc2[2][0] += m01 * w.z; acc2[2][1] += m23 * w.z;
        acc2[3][0] += m01 * w.w; acc2[3][1] += m23 * w.w;
    }

    {
#pragma unroll
        for (int p = 0; p < 2; ++p)
#pragma unroll
            for (int l = 0; l < 2; ++l) {
                int n = n0b + 4 * png + 2 * p + l;
                if (n < N_NODES) {
                    ushort4 po = *(const ushort4*)(OP + (size_t)n * F_NODE + 4 * pcg);
                    float4 v;
                    v.x = fmaxf(acc2[0][p][l] + __uint_as_float((unsigned)po.x << 16), 0.f);
                    v.y = fmaxf(acc2[1][p][l] + __uint_as_float((unsigned)po.y << 16), 0.f);
                    v.z = fmaxf(acc2[2][p][l] + __uint_as_float((unsigned)po.z << 16), 0.f);
                    v.w = fmaxf(acc2[3][p][l] + __uint_as_float((unsigned)po.w << 16), 0.f);
                    *(float4*)(out + (size_t)n * F_NODE + 4 * pcg) = v;
                }
            }
    }
}

extern "C" void kernel_launch(void* const* d_in, const int* in_sizes, int n_in,
                              void* d_out, int out_size, void* d_ws, size_t ws_size,
                              hipStream_t stream) {
    const float* nf  = (const float*)d_in[0];
    const int*   idx = (const int*)d_in[1];
    const float* ef  = (const float*)d_in[2];
    const float* We  = (const float*)d_in[3];
    const float* be  = (const float*)d_in[4];
    const float* Wn  = (const float*)d_in[5];
    const float* bn  = (const float*)d_in[6];
    float* out = (float*)d_out;

    // ws: deg 0.2 + rank 2.4 + perm 2.4 + Q 3.2 + P0 3.2 + OP 12.8 = 24.2 MB
    int* deg  = (int*)d_ws;                  // 50000 (counts -> start offsets)
    int* rank = deg + N_NODES;               // 600000
    int* perm = rank + N_EDGES;              // 600000
    unsigned short* Q   = (unsigned short*)(perm + N_EDGES);   // [N][32] bf16
    unsigned short* P0g = Q + (size_t)N_NODES * MSG;           // [N][32] bf16
    unsigned short* OP  = P0g + (size_t)N_NODES * MSG;         // [N][128] bf16

    hipMemsetAsync(deg, 0, (size_t)N_NODES * sizeof(int), stream);

    hist_kernel<<<2 * QB64 + CBLOCKS, 256, 0, stream>>>(
        nf, We, be, Wn, bn, idx, Q, P0g, OP, deg, rank);
    scan_kernel<<<1, 1024, 0, stream>>>(deg);
    place_kernel<<<CBLOCKS, 256, 0, stream>>>(idx, deg, rank, perm);

    fused_kernel<<<FBLOCKS, 256, 0, stream>>>(
        nf, idx, ef, We, Wn, perm, deg, Q, P0g, OP, out);
}

// Round 10
// 321.458 us; speedup vs baseline: 2.0385x; 2.0385x over previous
//
#include <hip/hip_runtime.h>

#define N_NODES 50000
#define N_EDGES 600000
#define F_NODE 128
#define F_EDGE 32
#define MSG 32
#define NPB 32          // nodes per fused block -> 1563 blocks (6.1/CU)
#define CHK 128         // edges per chunk
#define QB64 ((N_NODES + 63) / 64)                 // 782 (prep GEMM tiles)
#define FBLOCKS ((N_NODES + NPB - 1) / NPB)        // 1563
#define CBLOCKS ((N_EDGES + 255) / 256)            // 2344

typedef float v2f __attribute__((ext_vector_type(2)));   // -> v_pk_fma_f32

// bf16 helpers
__device__ __forceinline__ unsigned short f2bf(float f) {
    union { float f; unsigned int u; } v; v.f = f;
    unsigned int r = v.u + 0x7fffu + ((v.u >> 16) & 1u);
    return (unsigned short)(r >> 16);
}

// Raw barrier: lgkmcnt(0)-only fence + s_barrier (no vmcnt drain ->
// prefetched global loads stay in flight across barriers).
#define BAR_LGKM() do {                                           \
    asm volatile("s_waitcnt lgkmcnt(0)" ::: "memory");            \
    __builtin_amdgcn_s_barrier();                                 \
    asm volatile("" ::: "memory");                                \
} while (0)

// ---------------------------------------------------------------------------
// hist_kernel, 3 block ranges (proven correct in round 9):
//  [0, QB64): dual node-term GEMM  P0 = nf@We[0:128]+be, Q = nf@We[128:256]
//  [QB64, 2*QB64): OP = nf@Wn[0:128] + bn -> bf16
//  [2*QB64, ..): degree histogram WITH RANK CAPTURE (rank[e] = old count)
// ---------------------------------------------------------------------------
__global__ __launch_bounds__(256)
void hist_kernel(const float* __restrict__ nf,
                 const float* __restrict__ We,     // [288][32]
                 const float* __restrict__ be,     // [32]
                 const float* __restrict__ Wn,     // [160][128]
                 const float* __restrict__ bn,     // [128]
                 const int* __restrict__ idx,      // [2][E]
                 unsigned short* __restrict__ Q,   // [N][32] bf16
                 unsigned short* __restrict__ P0g, // [N][32] bf16
                 unsigned short* __restrict__ OP,  // [N][128] bf16
                 int* __restrict__ deg,            // [N] counts
                 int* __restrict__ rank)           // [E]
{
    __shared__ __align__(16) float S[6144];
    const int tid = threadIdx.x;

    if (blockIdx.x >= 2 * QB64) {
        int e = (blockIdx.x - 2 * QB64) * 256 + tid;
        if (e < N_EDGES) {
            int n = idx[e];
            if ((unsigned)n >= (unsigned)N_NODES) n = 0;
            rank[e] = atomicAdd(&deg[n], 1);
        }
        return;
    }

    if (blockIdx.x >= QB64) {
        // ---- branch B: OP = nf @ Wn[0:128] + bn -> bf16 ----
        float* sInT = S;            // [32][64]
        float* sWn  = S + 2048;     // [32][128]
        const int n0b = (blockIdx.x - QB64) * 64;
        const int png2 = tid >> 4;  // nodes 4*png2..+3
        const int pcg2 = tid & 15;  // cols 4*pcg2..+3 and 64+4*pcg2..+3

        v2f accC[8][2];             // [col j][node pair p]
#pragma unroll
        for (int j = 0; j < 8; ++j) { accC[j][0] = (v2f){0.f,0.f}; accC[j][1] = (v2f){0.f,0.f}; }

        for (int kc = 0; kc < 4; ++kc) {
            __syncthreads();
            {
                const float4* w4 = (const float4*)(Wn + (size_t)kc * 32 * 128);
                float4* s4 = (float4*)sWn;
#pragma unroll
                for (int i = 0; i < 4; ++i) s4[tid + 256 * i] = w4[tid + 256 * i];
            }
            {
                int nl = tid >> 2, q = tid & 3;
                int n = n0b + nl; if (n >= N_NODES) n = N_NODES - 1;
                const float4* src4 = (const float4*)(nf + (size_t)n * F_NODE + kc * 32);
#pragma unroll
                for (int h = 0; h < 2; ++h) {
                    float4 v = src4[q * 2 + h];
                    int kl = q * 8 + h * 4;
                    sInT[(kl + 0) * 64 + nl] = v.x;
                    sInT[(kl + 1) * 64 + nl] = v.y;
                    sInT[(kl + 2) * 64 + nl] = v.z;
                    sInT[(kl + 3) * 64 + nl] = v.w;
                }
            }
            __syncthreads();
#pragma unroll
            for (int k = 0; k < 32; ++k) {
                float4 m4 = *(const float4*)&sInT[k * 64 + 4 * png2];
                float4 w0 = *(const float4*)&sWn[k * 128 + 4 * pcg2];
                float4 w1 = *(const float4*)&sWn[k * 128 + 64 + 4 * pcg2];
                v2f m01 = (v2f){m4.x, m4.y}, m23 = (v2f){m4.z, m4.w};
                accC[0][0] += m01 * w0.x; accC[0][1] += m23 * w0.x;
                accC[1][0] += m01 * w0.y; accC[1][1] += m23 * w0.y;
                accC[2][0] += m01 * w0.z; accC[2][1] += m23 * w0.z;
                accC[3][0] += m01 * w0.w; accC[3][1] += m23 * w0.w;
                accC[4][0] += m01 * w1.x; accC[4][1] += m23 * w1.x;
                accC[5][0] += m01 * w1.y; accC[5][1] += m23 * w1.y;
                accC[6][0] += m01 * w1.z; accC[6][1] += m23 * w1.z;
                accC[7][0] += m01 * w1.w; accC[7][1] += m23 * w1.w;
            }
        }
        float4 b0 = *(const float4*)(bn + 4 * pcg2);
        float4 b1 = *(const float4*)(bn + 64 + 4 * pcg2);
#pragma unroll
        for (int p = 0; p < 2; ++p)
#pragma unroll
            for (int l = 0; l < 2; ++l) {
                int n = n0b + 4 * png2 + 2 * p + l;
                if (n < N_NODES) {
                    ushort4 o0, o1;
                    o0.x = f2bf(accC[0][p][l] + b0.x);
                    o0.y = f2bf(accC[1][p][l] + b0.y);
                    o0.z = f2bf(accC[2][p][l] + b0.z);
                    o0.w = f2bf(accC[3][p][l] + b0.w);
                    o1.x = f2bf(accC[4][p][l] + b1.x);
                    o1.y = f2bf(accC[5][p][l] + b1.y);
                    o1.z = f2bf(accC[6][p][l] + b1.z);
                    o1.w = f2bf(accC[7][p][l] + b1.w);
                    *(ushort4*)(OP + (size_t)n * F_NODE + 4 * pcg2) = o0;
                    *(ushort4*)(OP + (size_t)n * F_NODE + 64 + 4 * pcg2) = o1;
                }
            }
        return;
    }

    // ---- branch A: dual P0/Q GEMM (proven) ----
    {
        float* sInT = S;            // [32][64]
        float* sWeA = S + 2048;     // [32][32]
        float* sWeB = S + 3072;     // [32][32]
        const int n0b = blockIdx.x * 64;
        const int ng = tid & 31;
        const int og = tid >> 5;

        v2f accA[4], accB[4];
#pragma unroll
        for (int j = 0; j < 4; ++j) { accA[j] = (v2f){0.f, 0.f}; accB[j] = (v2f){0.f, 0.f}; }

        for (int kc = 0; kc < 4; ++kc) {
            __syncthreads();
            ((float4*)sWeA)[tid] = ((const float4*)(We + kc * 32 * MSG))[tid];
            ((float4*)sWeB)[tid] = ((const float4*)(We + (128 + kc * 32) * MSG))[tid];
            {
                int nl = tid >> 2, q = tid & 3;
                int n = n0b + nl; if (n >= N_NODES) n = N_NODES - 1;
                const float4* src4 = (const float4*)(nf + (size_t)n * F_NODE + kc * 32);
#pragma unroll
                for (int h = 0; h < 2; ++h) {
                    float4 v = src4[q * 2 + h];
                    int kl = q * 8 + h * 4;
                    sInT[(kl + 0) * 64 + nl] = v.x;
                    sInT[(kl + 1) * 64 + nl] = v.y;
                    sInT[(kl + 2) * 64 + nl] = v.z;
                    sInT[(kl + 3) * 64 + nl] = v.w;
                }
            }
            __syncthreads();
#pragma unroll
            for (int k = 0; k < 32; ++k) {
                v2f m = *(const v2f*)&sInT[k * 64 + 2 * ng];
                float4 wa = *(const float4*)&sWeA[k * 32 + og * 4];
                float4 wb = *(const float4*)&sWeB[k * 32 + og * 4];
                accA[0] += m * wa.x; accA[1] += m * wa.y;
                accA[2] += m * wa.z; accA[3] += m * wa.w;
                accB[0] += m * wb.x; accB[1] += m * wb.y;
                accB[2] += m * wb.z; accB[3] += m * wb.w;
            }
        }
        float bloc[4];
#pragma unroll
        for (int j = 0; j < 4; ++j) bloc[j] = be[og * 4 + j];
#pragma unroll
        for (int i = 0; i < 2; ++i) {
            int n = n0b + 2 * ng + i;
            if (n < N_NODES) {
                ushort4 oq, op;
                oq.x = f2bf(accB[0][i]); oq.y = f2bf(accB[1][i]);
                oq.z = f2bf(accB[2][i]); oq.w = f2bf(accB[3][i]);
                op.x = f2bf(accA[0][i] + bloc[0]); op.y = f2bf(accA[1][i] + bloc[1]);
                op.z = f2bf(accA[2][i] + bloc[2]); op.w = f2bf(accA[3][i] + bloc[3]);
                *(ushort4*)(Q   + (size_t)n * MSG + og * 4) = oq;
                *(ushort4*)(P0g + (size_t)n * MSG + og * 4) = op;
            }
        }
    }
}

// ---------------------------------------------------------------------------
// scan v3 (proven): int4 per thread, in-place exclusive scan counts->starts.
// ---------------------------------------------------------------------------
__global__ __launch_bounds__(1024)
void scan_kernel(int* __restrict__ deg_cursor) {
    __shared__ int wsum[16];
    __shared__ int wpre[16];
    const int t = threadIdx.x;
    const int lane = t & 63;
    const int wid = t >> 6;
    const int N4 = N_NODES / 4;              // 12500
    const int NT = (N4 + 1023) / 1024;       // 13
    int run = 0;
    int4 vnext = make_int4(0, 0, 0, 0);
    if (t < N4) vnext = ((const int4*)deg_cursor)[t];
    for (int tt = 0; tt < NT; ++tt) {
        int4 v = vnext;
        if (tt + 1 < NT) {
            int ni = (tt + 1) * 1024 + t;
            vnext = (ni < N4) ? ((const int4*)deg_cursor)[ni] : make_int4(0, 0, 0, 0);
        }
        int s = v.x + v.y + v.z + v.w;
        int x = s;
#pragma unroll
        for (int d = 1; d < 64; d <<= 1) {
            int u = __shfl_up(x, (unsigned)d, 64);
            if (lane >= d) x += u;
        }
        if (lane == 63) wsum[wid] = x;
        BAR_LGKM();
        if (wid == 0) {
            int ss = (lane < 16) ? wsum[lane] : 0;
#pragma unroll
            for (int d = 1; d < 16; d <<= 1) {
                int u = __shfl_up(ss, (unsigned)d, 64);
                if (lane >= d) ss += u;
            }
            if (lane < 16) wpre[lane] = ss;
        }
        BAR_LGKM();
        int wexcl = (wid > 0) ? wpre[wid - 1] : 0;
        int total = wpre[15];
        int i4 = tt * 1024 + t;
        if (i4 < N4) {
            int base = run + wexcl + (x - s);
            int4 o;
            o.x = base;
            o.y = base + v.x;
            o.z = base + v.x + v.y;
            o.w = base + v.x + v.y + v.z;
            ((int4*)deg_cursor)[i4] = o;
        }
        run += total;
        BAR_LGKM();
    }
}

// ---------------------------------------------------------------------------
// place: perm[start[n] + rank[e]] = e — NO atomics. (proven)
// ---------------------------------------------------------------------------
__global__ void place_kernel(const int* __restrict__ idx,
                             const int* __restrict__ startArr,
                             const int* __restrict__ rank,
                             int* __restrict__ perm) {
    int e = blockIdx.x * 256 + threadIdx.x;
    if (e < N_EDGES) {
        int n = idx[e];
        if ((unsigned)n >= (unsigned)N_NODES) n = 0;
        int p = startArr[n] + rank[e];
        if ((unsigned)p < (unsigned)N_EDGES) perm[p] = e;
    }
}

// ---------------------------------------------------------------------------
// Fused kernel v10 — v9 structure, VGPR cap RELAXED. v9 lesson: under
// __launch_bounds__(256,4) this body went scratch-resident (VGPR_Count 64,
// WRITE 928 MB, dur 483 µs). LDS (39,936 B) already caps occupancy at
// 4 blocks/CU, so the 128-VGPR cap bought nothing — it could only force
// spills. __launch_bounds__(256) lets the allocator pick its natural
// allocation (~80-110 est.; v7's similar body used 52).
//   out = relu(OP + msum @ Wn[128:160]); phase-2 LDS ops ~340 -> ~72.
// LDS map (floats): [0,4096) sBuf | [4096,8192) sMsg | [8192,9216) sWeC
//   | [9216,9728) sP0h(u16) | [9728,9856) sNL | [9856..] sOff
// Phase2 overlay: sWn2 = S[0,4096), sInT2 = S+4096.
// ---------------------------------------------------------------------------
__global__ __launch_bounds__(256)
void fused_kernel(const int* __restrict__ idx,      // [2][E]
                  const float* __restrict__ ef,     // [E][32]
                  const float* __restrict__ We,     // [288][32]
                  const float* __restrict__ Wn,     // [160][128]
                  const int* __restrict__ perm,     // [E] sorted edge ids
                  const int* __restrict__ startArr, // [N] start offsets
                  const unsigned short* __restrict__ Q,    // [N][32] bf16
                  const unsigned short* __restrict__ P0g,  // [N][32] bf16
                  const unsigned short* __restrict__ OP,   // [N][128] bf16
                  float* __restrict__ out)          // [N][128]
{
    __shared__ __align__(16) float S[9892];
    float* sBuf = S;                                  // [32][128] ef^T
    float* sMsg = S + 4096;                           // [32][128] msgT
    float* sWeC = S + 8192;                           // [32][32] We_bot
    unsigned short* sP0h = (unsigned short*)(S + 9216); // [32][32] bf16
    int* sNL  = (int*)(S + 9728);                     // [128] (ln<<20)|n1
    int* sOff = (int*)(S + 9856);                     // [33]
    float* sWn2  = S;                                 // phase2 Wn bottom slab
    float* sInT2 = S + 4096;                          // phase2 msum^T (overlay)

    const int tid = threadIdx.x;
    const int n0b = blockIdx.x * NPB;

    if (tid <= NPB) {
        int nn = n0b + tid;
        int v = (nn < N_NODES) ? startArr[nn] : N_EDGES;
        if (v < 0) v = 0;
        if (v > N_EDGES) v = N_EDGES;
        sOff[tid] = v;
    }
    ((float4*)sWeC)[tid] = ((const float4*)(We + 256 * MSG))[tid];  // We_bot
    if (tid < 128) {   // P0 rows for this block's 32 nodes (2 KB coalesced)
        int r = tid >> 2, c = (tid & 3) * 8;
        int n = n0b + r; if (n >= N_NODES) n = N_NODES - 1;
        *(uint4*)(sP0h + r * MSG + c) = *(const uint4*)(P0g + (size_t)n * MSG + c);
    }
    __syncthreads();

    const int rs = sOff[0];
    const int re = sOff[NPB];

    // persistent per-thread message sums: thread = (node rnl, cols rq4..+3)
    float msum[4];
#pragma unroll
    for (int j = 0; j < 4; ++j) msum[j] = 0.f;
    const int rnl = tid >> 3;            // node 0..31
    const int rq4 = (tid & 7) * 4;       // col group
    const int gx  = (rq4 >> 3) << 2;     // reduce-phase swizzle (matches store)

    const int eq = tid & 31;   // GEMM: edges 4eq..4eq+3
    const int cq = tid >> 5;   // GEMM: cols 4cq..4cq+3
    const int g1 = (cq >> 1) & 3;        // store row-group swizzle (const/thread)
    const int el = tid >> 1;   // staged edge slot 0..127
    const int h2 = tid & 1;    // which half of the ef row

    // ---- prefetch pipeline registers -------------------------------------
    int n1r = 0;                     // n1 for chunk i (h2==0 lanes)
    int pe_next = 0, pe_next2 = 0;   // perm for chunk i+1 / in flight i+2
    float4 efr[4];                   // my ef half-row for chunk i
#pragma unroll
    for (int q = 0; q < 4; ++q) efr[q] = make_float4(0.f, 0.f, 0.f, 0.f);

    if (rs < re) {
        int e0 = rs + el;
        int pe0 = 0;
        if (e0 < re) {
            pe0 = perm[e0];
            if ((unsigned)pe0 >= (unsigned)N_EDGES) pe0 = 0;   // poison guard
            if (h2 == 0) {
                int tn = idx[N_EDGES + pe0];
                if ((unsigned)tn >= (unsigned)N_NODES) tn = 0;
                n1r = tn;
            }
        }
        const float4* ef4 = (const float4*)(ef + (size_t)pe0 * F_EDGE + h2 * 16);
#pragma unroll
        for (int q = 0; q < 4; ++q) efr[q] = ef4[q];
        int e1 = rs + CHK + el;
        if (e1 < re) {
            int p = perm[e1];
            if ((unsigned)p >= (unsigned)N_EDGES) p = 0;
            pe_next = p;
        }
        pe_next2 = pe_next;          // bootstrap rotation for iter 0
    }

    // ================= Chunk loop (2 barriers) ============================
    for (int cs = rs; cs < re; cs += CHK) {
        pe_next = pe_next2;
        {
            // ---- stage ef^T(i) into sBuf (k-major, swizzled) ----
#pragma unroll
            for (int q = 0; q < 4; ++q) {
                float4 v = efr[q];
                int g = (h2 * 2 + (q >> 1)) & 3;              // (row>>3)&3 of this quad
                int ctw = ((el & ~3) ^ (g << 2)) + (el & 3);
                int r0 = (h2 * 16 + q * 4) * CHK;
                sBuf[r0 + 0 * CHK + ctw] = v.x;
                sBuf[r0 + 1 * CHK + ctw] = v.y;
                sBuf[r0 + 2 * CHK + ctw] = v.z;
                sBuf[r0 + 3 * CHK + ctw] = v.w;
            }
            // ---- ln (binary search over sOff[0..32]) + packed sNL ----
            if (h2 == 0) {
                int e = cs + el;
                int ln = 0;
                if (e < re) {
                    int lo = 0, hi = NPB;
#pragma unroll
                    for (int s = 0; s < 5; ++s) {
                        int mid = (lo + hi) >> 1;
                        if (sOff[mid] <= e) lo = mid; else hi = mid;
                    }
                    ln = lo;
                }
                sNL[el] = (ln << 20) | n1r;
            }
            // ---- issue gathers for chunk i+1 ----
            int e1 = cs + CHK + el;
            if (e1 < re) {
                int pe1 = pe_next;
                if (h2 == 0) {
                    int tn = idx[N_EDGES + pe1];
                    if ((unsigned)tn >= (unsigned)N_NODES) tn = 0;
                    n1r = tn;
                }
                const float4* ef4 = (const float4*)(ef + (size_t)pe1 * F_EDGE + h2 * 16);
#pragma unroll
                for (int q = 0; q < 4; ++q) efr[q] = ef4[q];
            } else if (h2 == 0) n1r = 0;
            // ---- issue perm for chunk i+2 ----
            int e2 = cs + 2 * CHK + el;
            if (e2 < re) {
                int p = perm[e2];
                if ((unsigned)p >= (unsigned)N_EDGES) p = 0;
                pe_next2 = p;
            } else pe_next2 = 0;
        }
        BAR_LGKM();        // (A) staging visible; prev reduce done (>=1 bar ago)

        // Q gather (4 edges x 4 cols = uint2 each), in flight during GEMM
        int4 nlq = *(const int4*)&sNL[4 * eq];
        int nlv[4] = { nlq.x, nlq.y, nlq.z, nlq.w };
        uint2 qv[4];
#pragma unroll
        for (int i = 0; i < 4; ++i)
            qv[i] = *(const uint2*)(Q + (size_t)(nlv[i] & 0xFFFFF) * MSG + cq * 4);

        v2f accp[4][2];                    // [col j][edge pair p]
#pragma unroll
        for (int j = 0; j < 4; ++j) { accp[j][0] = (v2f){0.f,0.f}; accp[j][1] = (v2f){0.f,0.f}; }

#pragma unroll
        for (int k = 0; k < 32; ++k) {
            float4 m4 = *(const float4*)&sBuf[k * CHK + ((4 * eq) ^ (((k >> 3) & 3) << 2))];
            float4 w  = *(const float4*)&sWeC[k * 32 + cq * 4];
            v2f m01 = (v2f){m4.x, m4.y}, m23 = (v2f){m4.z, m4.w};
            accp[0][0] += m01 * w.x; accp[0][1] += m23 * w.x;
            accp[1][0] += m01 * w.y; accp[1][1] += m23 * w.y;
            accp[2][0] += m01 * w.z; accp[2][1] += m23 * w.z;
            accp[3][0] += m01 * w.w; accp[3][1] += m23 * w.w;
        }

        // ---- +P0 +Q, relu, store msgT[col][edge] (b128 along edges) ----
        {
            uint2 pv[4];
#pragma unroll
            for (int i = 0; i < 4; ++i)
                pv[i] = *(const uint2*)(sP0h + (nlv[i] >> 20) * MSG + cq * 4);
            int sb = (4 * eq) ^ (g1 << 2);
#pragma unroll
            for (int j = 0; j < 4; ++j) {
                float sv[4];
#pragma unroll
                for (int i = 0; i < 4; ++i) {
                    unsigned qu = (j < 2) ? qv[i].x : qv[i].y;
                    unsigned pu = (j < 2) ? pv[i].x : pv[i].y;
                    float qf = __uint_as_float((j & 1) ? (qu & 0xffff0000u) : (qu << 16));
                    float pf = __uint_as_float((j & 1) ? (pu & 0xffff0000u) : (pu << 16));
                    sv[i] = fmaxf(accp[j][i >> 1][i & 1] + pf + qf, 0.f);
                }
                *(float4*)&sMsg[(cq * 4 + j) * CHK + sb] =
                    make_float4(sv[0], sv[1], sv[2], sv[3]);
            }
        }
        BAR_LGKM();        // (B) msgT visible; sBuf reads done (next stage safe)

        // ---- segmented reduction (no atomics): my node's range this chunk
        {
            int lo = sOff[rnl] - cs;     if (lo < 0) lo = 0;
            int hi = sOff[rnl + 1] - cs; if (hi > CHK) hi = CHK;
            for (int elr = lo; elr < hi; ++elr) {
                int ebase = ((elr & ~3) ^ gx) + (elr & 3);
#pragma unroll
                for (int j = 0; j < 4; ++j)
                    msum[j] += sMsg[(rq4 + j) * CHK + ebase];
            }
        }
    }

    // ====== Phase 2 (one slab): out = relu(OP + msum @ Wn[128:160]) ======
    const int png = tid & 7;       // nodes 4*png..+3
    const int pcg = tid >> 3;      // cols 4*pcg..+3

    __syncthreads();               // chunk-loop LDS reads done; overlay safe
    {
        const float4* w4 = (const float4*)(Wn + (size_t)128 * 128);
        float4* s4 = (float4*)sWn2;
#pragma unroll
        for (int i = 0; i < 4; ++i) s4[tid + 256 * i] = w4[tid + 256 * i];
        // thread (rnl, rq4) owns exactly msum for node rnl, cols rq4..+3
#pragma unroll
        for (int h = 0; h < 4; ++h) {
            int r = rq4 + h;
            sInT2[r * 32 + (rnl ^ ((r & 7) << 2))] = msum[h];
        }
    }
    __syncthreads();

    v2f acc2[4][2];                // [col j][node pair p]
#pragma unroll
    for (int j = 0; j < 4; ++j) { acc2[j][0] = (v2f){0.f,0.f}; acc2[j][1] = (v2f){0.f,0.f}; }

#pragma unroll
    for (int k = 0; k < 32; ++k) {
        float4 m4 = *(const float4*)&sInT2[k * 32 + ((4 * png) ^ ((k & 7) << 2))];
        float4 w  = *(const float4*)&sWn2[k * 128 + 4 * pcg];
        v2f m01 = (v2f){m4.x, m4.y}, m23 = (v2f){m4.z, m4.w};
        acc2[0][0] += m01 * w.x; acc2[0][1] += m23 * w.x;
        acc2[1][0] += m01 * w.y; acc2[1][1] += m23 * w.y;
        acc2[2][0] += m01 * w.z; acc2[2][1] += m23 * w.z;
        acc2[3][0] += m01 * w.w; acc2[3][1] += m23 * w.w;
    }

    {
#pragma unroll
        for (int p = 0; p < 2; ++p)
#pragma unroll
            for (int l = 0; l < 2; ++l) {
                int n = n0b + 4 * png + 2 * p + l;
                if (n < N_NODES) {
                    ushort4 po = *(const ushort4*)(OP + (size_t)n * F_NODE + 4 * pcg);
                    float4 v;
                    v.x = fmaxf(acc2[0][p][l] + __uint_as_float((unsigned)po.x << 16), 0.f);
                    v.y = fmaxf(acc2[1][p][l] + __uint_as_float((unsigned)po.y << 16), 0.f);
                    v.z = fmaxf(acc2[2][p][l] + __uint_as_float((unsigned)po.z << 16), 0.f);
                    v.w = fmaxf(acc2[3][p][l] + __uint_as_float((unsigned)po.w << 16), 0.f);
                    *(float4*)(out + (size_t)n * F_NODE + 4 * pcg) = v;
                }
            }
    }
}

extern "C" void kernel_launch(void* const* d_in, const int* in_sizes, int n_in,
                              void* d_out, int out_size, void* d_ws, size_t ws_size,
                              hipStream_t stream) {
    const float* nf  = (const float*)d_in[0];
    const int*   idx = (const int*)d_in[1];
    const float* ef  = (const float*)d_in[2];
    const float* We  = (const float*)d_in[3];
    const float* be  = (const float*)d_in[4];
    const float* Wn  = (const float*)d_in[5];
    const float* bn  = (const float*)d_in[6];
    float* out = (float*)d_out;

    // ws: deg 0.2 + rank 2.4 + perm 2.4 + Q 3.2 + P0 3.2 + OP 12.8 = 24.2 MB
    int* deg  = (int*)d_ws;                  // 50000 (counts -> start offsets)
    int* rank = deg + N_NODES;               // 600000
    int* perm = rank + N_EDGES;              // 600000
    unsigned short* Q   = (unsigned short*)(perm + N_EDGES);   // [N][32] bf16
    unsigned short* P0g = Q + (size_t)N_NODES * MSG;           // [N][32] bf16
    unsigned short* OP  = P0g + (size_t)N_NODES * MSG;         // [N][128] bf16

    hipMemsetAsync(deg, 0, (size_t)N_NODES * sizeof(int), stream);

    hist_kernel<<<2 * QB64 + CBLOCKS, 256, 0, stream>>>(
        nf, We, be, Wn, bn, idx, Q, P0g, OP, deg, rank);
    scan_kernel<<<1, 1024, 0, stream>>>(deg);
    place_kernel<<<CBLOCKS, 256, 0, stream>>>(idx, deg, rank, perm);

    fused_kernel<<<FBLOCKS, 256, 0, stream>>>(
        idx, ef, We, Wn, perm, deg, Q, P0g, OP, out);
}